// Round 8
// baseline (35.694 us; speedup 1.0000x reference)
//
#include <hip/hip_runtime.h>

// Problem constants (from reference: x [16, 32, 64, 32, 32] f32)
constexpr int T_DIM   = 16;
constexpr int B_DIM   = 32;
constexpr int FEAT    = 64 * 32 * 32;   // 65536 features per (t,b)
constexpr int THREADS = 256;
constexpr int NCHUNK  = 32;             // blocks per b -> 1024 blocks
constexpr int FPB     = FEAT / NCHUNK;  // 2048 features per block
constexpr int ITERS   = FPB / 512;      // 4 (per iter: 4 waves x 32 f4 x 4)

// Pass 1: t-split (lanes 0-31 own t=0..7, lanes 32-63 own t=8..15 of the SAME
// feature groups), relu+cumsum IN PLACE in the load registers, manual 2-deep
// LOAD/PROC pipeline with statically-named buffers vA/vB.
// Round 6 measured this body at VGPR_Count=84 -> 6 blocks/CU -> all 1024
// blocks resident in ONE round (rounds 1/4/7 free-unrolled to ~3 blocks/CU and
// paid a ~1.3x residency tail). No launch_bounds cap (w=4 spilled 50 MB,
// measured r2/r3), no unroll pragmas (unroll 1 cost 3.5 us, measured r5).
__global__ __launch_bounds__(THREADS) void snn_pass1(
    const float* __restrict__ x, float* __restrict__ partial) {
    const int b     = blockIdx.x;   // 0..31
    const int chunk = blockIdx.y;   // 0..31
    const int tid   = threadIdx.x;
    const int lane  = tid & 63;
    const int wave  = tid >> 6;
    const int half  = lane >> 5;    // 0: t=0..7, 1: t=8..15
    const int sub   = lane & 31;

    const size_t tstride  = (size_t)B_DIM * FEAT;  // floats between t-planes
    const size_t tstride4 = tstride / 4;           // in float4 units
    const float* xb = x + (size_t)b * FEAT + (size_t)half * 8 * tstride;

    float accA[8], accB[8];
#pragma unroll
    for (int k = 0; k < 8; ++k) { accA[k] = 0.f; accB[k] = 0.f; }

    float4 vA[8], vB[8];

    auto LOAD = [&](float4 (&v)[8], int it) {
        const int f = chunk * FPB + (it * 128 + wave * 32 + sub) * 4;
        const float4* p = reinterpret_cast<const float4*>(xb + f);
#pragma unroll
        for (int k = 0; k < 8; ++k) v[k] = p[(size_t)k * tstride4];
    };

    auto PROC = [&](float4 (&v)[8]) {
        // relu + in-place cumsum: v[k] becomes s[half*8+k]
        float4 run = make_float4(0.f, 0.f, 0.f, 0.f);
#pragma unroll
        for (int k = 0; k < 8; ++k) {
            run.x += fmaxf(v[k].x, 0.f);
            run.y += fmaxf(v[k].y, 0.f);
            run.z += fmaxf(v[k].z, 0.f);
            run.w += fmaxf(v[k].w, 0.f);
            v[k] = run;
        }
        // cross-half stitch: 4 shuffles
        float4 other;
        other.x = __shfl_xor(run.x, 32, 64);
        other.y = __shfl_xor(run.y, 32, 64);
        other.z = __shfl_xor(run.z, 32, 64);
        other.w = __shfl_xor(run.w, 32, 64);
        const float4 s15 = make_float4(run.x + other.x, run.y + other.y,
                                       run.z + other.z, run.w + other.w);
        const float hb = (float)half;  // upper half adds lower's s[7] as base
        const float bx = other.x * hb, by = other.y * hb,
                    bz = other.z * hb, bw = other.w * hb;
#pragma unroll
        for (int k = 0; k < 8; ++k) {
            const float invt = half ? (1.f / (float)(k + 9))
                                    : (1.f / (float)(k + 1));
            const float sx = v[k].x + bx, sy = v[k].y + by,
                        sz = v[k].z + bz, sw = v[k].w + bw;
            accA[k] += (sx * sx + sy * sy + sz * sz + sw * sw) * (invt * invt);
            accB[k] += (sx * s15.x + sy * s15.y + sz * s15.z + sw * s15.w)
                       * (invt * 0.0625f);
        }
    };

    // Manual 2-deep pipeline over ITERS=4 (all names static, no dyn indexing).
    LOAD(vA, 0);
    LOAD(vB, 1);
    PROC(vA);
    LOAD(vA, 2);
    PROC(vB);
    LOAD(vB, 3);
    PROC(vA);
    PROC(vB);

    // Reduce within each 32-lane half (xor masks <32 stay inside the half).
#pragma unroll
    for (int k = 0; k < 8; ++k) {
#pragma unroll
        for (int m = 16; m; m >>= 1) {
            accA[k] += __shfl_xor(accA[k], m, 64);
            accB[k] += __shfl_xor(accB[k], m, 64);
        }
    }

    __shared__ float red[4][32];
    if (sub == 0) {  // lane 0 (t=0..7) and lane 32 (t=8..15) per wave
#pragma unroll
        for (int k = 0; k < 8; ++k) {
            red[wave][half * 8 + k]      = accA[k];
            red[wave][16 + half * 8 + k] = accB[k];
        }
    }
    __syncthreads();
    if (tid < 32) {
        const float s4 = red[0][tid] + red[1][tid] + red[2][tid] + red[3][tid];
        partial[((size_t)b * NCHUNK + chunk) * 32 + tid] = s4;
    }
}

// Pass 2: reduce chunks, finalize per-b scalar.
__global__ __launch_bounds__(64) void snn_finalize(
    const float* __restrict__ partial, float* __restrict__ out) {
    const int b   = blockIdx.x;   // 0..31
    const int tid = threadIdx.x;  // 64 threads = 1 wave
    const int v   = tid & 31;     // value index 0..31
    const int h   = tid >> 5;     // chunk half

    float acc = 0.f;
#pragma unroll
    for (int i = 0; i < NCHUNK / 2; ++i) {
        const int c = h * (NCHUNK / 2) + i;
        acc += partial[((size_t)b * NCHUNK + c) * 32 + v];
    }
    acc += __shfl_xor(acc, 32, 64);  // lanes 0..31 now hold full sums

    __shared__ float sA[16];
    __shared__ float sB[16];
    if (tid < 16)      sA[tid] = acc;
    else if (tid < 32) sB[tid - 16] = acc;
    __syncthreads();

    if (tid == 0) {
        const float n15 = sqrtf(sA[15] + 1e-5f);
        float csum = 0.f;
#pragma unroll
        for (int t = 0; t < 16; ++t) {
            const float nt = sqrtf(sA[t] + 1e-5f);
            csum += sB[t] / (nt * n15);
        }
        const float cs = csum * (1.f / 16.f);
        out[b] = 1.f / (cs + 1e-5f);
    }
}

extern "C" void kernel_launch(void* const* d_in, const int* in_sizes, int n_in,
                              void* d_out, int out_size, void* d_ws, size_t ws_size,
                              hipStream_t stream) {
    const float* x   = (const float*)d_in[0];  // [16, 32, 64, 32, 32]
    float* out       = (float*)d_out;          // [1, 32]
    float* partial   = (float*)d_ws;           // 32 * 32 * 32 floats = 128 KB

    dim3 grid1(B_DIM, NCHUNK);
    snn_pass1<<<grid1, THREADS, 0, stream>>>(x, partial);
    snn_finalize<<<B_DIM, 64, 0, stream>>>(partial, out);
}

// Round 9
// 30.221 us; speedup vs baseline: 1.1811x; 1.1811x over previous
//
#include <hip/hip_runtime.h>

// Problem constants (from reference: x [16, 32, 64, 32, 32] f32)
constexpr int T_DIM   = 16;
constexpr int B_DIM   = 32;
constexpr int FEAT    = 64 * 32 * 32;   // 65536 features per (t,b)
constexpr int THREADS = 256;
constexpr int NCHUNK  = 16;             // blocks per b -> 512 blocks total
constexpr int FPB     = FEAT / NCHUNK;  // 4096 features per block
// Per iter: 4 waves x 256 floats (half-wave lane: va+vb float4 pair) = 1024
constexpr int ITERS   = FPB / 1024;     // 4

// Pass 1: t-split (lanes 0-31 own t=0..7, lanes 32-63 own t=8..15 of the SAME
// features), relu+cumsum in place, 1KB-per-plane-per-iter loads (va/vb).
// NEW vs round 7:
//  * 512 blocks (NCHUNK=16): only 2 blocks/CU needed for full residency, so
//    ANY compiler VGPR choice keeps the grid in one round (r8 falsified the
//    forced-low-VGPR approach; this removes residency quantization entirely).
//  * sequential wave streams: wave w owns a contiguous 4KB window per plane,
//    walked 1KB per iteration -> 4x longer DRAM runs, half as many streams.
__global__ __launch_bounds__(THREADS) void snn_pass1(
    const float* __restrict__ x, float* __restrict__ partial) {
    const int b     = blockIdx.x;   // 0..31
    const int chunk = blockIdx.y;   // 0..NCHUNK-1
    const int tid   = threadIdx.x;
    const int lane  = tid & 63;
    const int wave  = tid >> 6;
    const int half  = lane >> 5;    // 0: t=0..7, 1: t=8..15
    const int sub   = lane & 31;

    const size_t tstride  = (size_t)B_DIM * FEAT;  // floats between t-planes
    const size_t tstride4 = tstride / 4;           // in float4 units
    const float* xb = x + (size_t)b * FEAT + (size_t)half * 8 * tstride;

    float accA[8], accB[8];
#pragma unroll
    for (int k = 0; k < 8; ++k) { accA[k] = 0.f; accB[k] = 0.f; }

#pragma unroll
    for (int it = 0; it < ITERS; ++it) {
        // wave-contiguous: wave w covers [w*4KB, (w+1)*4KB) of the block's
        // window, advancing 256 floats (1KB) per iteration.
        const int base = chunk * FPB + wave * 1024 + it * 256;
        const float4* p = reinterpret_cast<const float4*>(xb + base) + sub;

        float4 va[8], vb[8];
#pragma unroll
        for (int k = 0; k < 8; ++k) {
            va[k] = p[(size_t)k * tstride4];        // floats [0,128) of window
            vb[k] = p[(size_t)k * tstride4 + 32];   // floats [128,256)
        }

        // relu + in-place cumsum (va/vb become s[half*8+k])
        float4 ra = make_float4(0.f, 0.f, 0.f, 0.f);
        float4 rb = make_float4(0.f, 0.f, 0.f, 0.f);
#pragma unroll
        for (int k = 0; k < 8; ++k) {
            ra.x += fmaxf(va[k].x, 0.f); ra.y += fmaxf(va[k].y, 0.f);
            ra.z += fmaxf(va[k].z, 0.f); ra.w += fmaxf(va[k].w, 0.f);
            va[k] = ra;
            rb.x += fmaxf(vb[k].x, 0.f); rb.y += fmaxf(vb[k].y, 0.f);
            rb.z += fmaxf(vb[k].z, 0.f); rb.w += fmaxf(vb[k].w, 0.f);
            vb[k] = rb;
        }

        // cross-half stitch: 8 shuffles
        float4 oa, ob;
        oa.x = __shfl_xor(ra.x, 32, 64); oa.y = __shfl_xor(ra.y, 32, 64);
        oa.z = __shfl_xor(ra.z, 32, 64); oa.w = __shfl_xor(ra.w, 32, 64);
        ob.x = __shfl_xor(rb.x, 32, 64); ob.y = __shfl_xor(rb.y, 32, 64);
        ob.z = __shfl_xor(rb.z, 32, 64); ob.w = __shfl_xor(rb.w, 32, 64);

        const float4 s15a = make_float4(ra.x + oa.x, ra.y + oa.y,
                                        ra.z + oa.z, ra.w + oa.w);
        const float4 s15b = make_float4(rb.x + ob.x, rb.y + ob.y,
                                        rb.z + ob.z, rb.w + ob.w);
        const float hb = (float)half;  // upper half adds lower's s[7] as base
        const float4 ba = make_float4(oa.x * hb, oa.y * hb, oa.z * hb, oa.w * hb);
        const float4 bb = make_float4(ob.x * hb, ob.y * hb, ob.z * hb, ob.w * hb);

#pragma unroll
        for (int k = 0; k < 8; ++k) {
            const float invt = half ? (1.f / (float)(k + 9))
                                    : (1.f / (float)(k + 1));
            const float ax = va[k].x + ba.x, ay = va[k].y + ba.y,
                        az = va[k].z + ba.z, aw = va[k].w + ba.w;
            const float bx = vb[k].x + bb.x, by = vb[k].y + bb.y,
                        bz = vb[k].z + bb.z, bw = vb[k].w + bb.w;
            accA[k] += (ax * ax + ay * ay + az * az + aw * aw +
                        bx * bx + by * by + bz * bz + bw * bw) * (invt * invt);
            accB[k] += (ax * s15a.x + ay * s15a.y + az * s15a.z + aw * s15a.w +
                        bx * s15b.x + by * s15b.y + bz * s15b.z + bw * s15b.w)
                       * (invt * 0.0625f);
        }
    }

    // Reduce within each 32-lane half (xor masks <32 stay inside the half).
#pragma unroll
    for (int k = 0; k < 8; ++k) {
#pragma unroll
        for (int m = 16; m; m >>= 1) {
            accA[k] += __shfl_xor(accA[k], m, 64);
            accB[k] += __shfl_xor(accB[k], m, 64);
        }
    }

    __shared__ float red[4][32];
    if (sub == 0) {  // lane 0 (t=0..7) and lane 32 (t=8..15) per wave
#pragma unroll
        for (int k = 0; k < 8; ++k) {
            red[wave][half * 8 + k]      = accA[k];
            red[wave][16 + half * 8 + k] = accB[k];
        }
    }
    __syncthreads();
    if (tid < 32) {
        const float s4 = red[0][tid] + red[1][tid] + red[2][tid] + red[3][tid];
        partial[((size_t)b * NCHUNK + chunk) * 32 + tid] = s4;
    }
}

// Pass 2: reduce chunks, finalize per-b scalar.
__global__ __launch_bounds__(64) void snn_finalize(
    const float* __restrict__ partial, float* __restrict__ out) {
    const int b   = blockIdx.x;   // 0..31
    const int tid = threadIdx.x;  // 64 threads = 1 wave
    const int v   = tid & 31;     // value index 0..31
    const int h   = tid >> 5;     // chunk half

    float acc = 0.f;
#pragma unroll
    for (int i = 0; i < NCHUNK / 2; ++i) {
        const int c = h * (NCHUNK / 2) + i;
        acc += partial[((size_t)b * NCHUNK + c) * 32 + v];
    }
    acc += __shfl_xor(acc, 32, 64);  // lanes 0..31 now hold full sums

    __shared__ float sA[16];
    __shared__ float sB[16];
    if (tid < 16)      sA[tid] = acc;
    else if (tid < 32) sB[tid - 16] = acc;
    __syncthreads();

    if (tid == 0) {
        const float n15 = sqrtf(sA[15] + 1e-5f);
        float csum = 0.f;
#pragma unroll
        for (int t = 0; t < 16; ++t) {
            const float nt = sqrtf(sA[t] + 1e-5f);
            csum += sB[t] / (nt * n15);
        }
        const float cs = csum * (1.f / 16.f);
        out[b] = 1.f / (cs + 1e-5f);
    }
}

extern "C" void kernel_launch(void* const* d_in, const int* in_sizes, int n_in,
                              void* d_out, int out_size, void* d_ws, size_t ws_size,
                              hipStream_t stream) {
    const float* x   = (const float*)d_in[0];  // [16, 32, 64, 32, 32]
    float* out       = (float*)d_out;          // [1, 32]
    float* partial   = (float*)d_ws;           // 32 * 16 * 32 floats = 64 KB

    dim3 grid1(B_DIM, NCHUNK);
    snn_pass1<<<grid1, THREADS, 0, stream>>>(x, partial);
    snn_finalize<<<B_DIM, 64, 0, stream>>>(partial, out);
}